// Round 11
// baseline (884.717 us; speedup 1.0000x reference)
//
#include <hip/hip_runtime.h>
#include <cstdint>
#include <cstddef>

// Problem constants (match reference)
#define B_ 256
#define T_ 128
#define I_ 512
#define H_ 1024
#define O_ 512
static constexpr float ALPHA = 1.0f / 20.0f;   // DT/TAU
static constexpr float THR   = 1.0f;
static constexpr float S12   = 0.000244140625f; // 2^-12 (exact)

typedef _Float16 f16;
typedef __attribute__((ext_vector_type(8))) _Float16 f16x8;
typedef __attribute__((ext_vector_type(4))) float f32x4;

__device__ inline void gload_lds16(const void* gsrc, void* ldsdst) {
    __builtin_amdgcn_global_load_lds(
        (const __attribute__((address_space(1))) unsigned int*)gsrc,
        (__attribute__((address_space(3))) unsigned int*)ldsdst, 16, 0, 0);
}

// ---------------------------------------------------------------------------
// fp32 tiled GEMM (deep-fallback path only)
// ---------------------------------------------------------------------------
template<bool PERM_X, bool RELU>
__global__ __launch_bounds__(256)
void gemm128(const float* __restrict__ A, const float* __restrict__ Bw,
             const float* __restrict__ bias, float* __restrict__ C,
             int M, int N, int K) {
    constexpr int BM = 128, BN = 128, BK = 16, TM = 8, TN = 8;
    __shared__ float As[BK][BM];
    __shared__ float Bs[BK][BN + 4];

    const int tid = threadIdx.x;
    const int ntile = N / BN;
    const int bx = blockIdx.x % ntile;
    const int by = blockIdx.x / ntile;
    const int row0 = by * BM, col0 = bx * BN;
    const int tx = tid & 15;
    const int ty = tid >> 4;

    float acc[TM][TN] = {};

    for (int k0 = 0; k0 < K; k0 += BK) {
#pragma unroll
        for (int p = 0; p < 2; ++p) {
            int f = tid + p * 256;
            int r  = f >> 2;
            int kc = (f & 3) << 2;
            int m = row0 + r;
            const float* arow;
            if (PERM_X) {
                int t = m >> 8;
                int b = m & 255;
                arow = A + (size_t)(b * T_ + t) * K;
            } else {
                arow = A + (size_t)m * K;
            }
            float4 v = *reinterpret_cast<const float4*>(arow + k0 + kc);
            As[kc + 0][r] = v.x;
            As[kc + 1][r] = v.y;
            As[kc + 2][r] = v.z;
            As[kc + 3][r] = v.w;
        }
#pragma unroll
        for (int p = 0; p < 2; ++p) {
            int f = tid + p * 256;
            int r  = f >> 5;
            int nc = (f & 31) << 2;
            float4 v = *reinterpret_cast<const float4*>(Bw + (size_t)(k0 + r) * N + col0 + nc);
            *reinterpret_cast<float4*>(&Bs[r][nc]) = v;
        }
        __syncthreads();

#pragma unroll
        for (int k = 0; k < BK; ++k) {
            float a[TM], b[TN];
#pragma unroll
            for (int i = 0; i < TM; ++i) a[i] = As[k][ty * TM + i];
#pragma unroll
            for (int j = 0; j < TN; ++j) b[j] = Bs[k][tx * TN + j];
#pragma unroll
            for (int i = 0; i < TM; ++i)
#pragma unroll
                for (int j = 0; j < TN; ++j)
                    acc[i][j] += a[i] * b[j];
        }
        __syncthreads();
    }

#pragma unroll
    for (int i = 0; i < TM; ++i) {
        size_t m = (size_t)(row0 + ty * TM + i);
#pragma unroll
        for (int jj = 0; jj < TN; jj += 4) {
            int n = col0 + tx * TN + jj;
            float4 c4;
            float c0 = acc[i][jj + 0] + bias[n + 0];
            float c1 = acc[i][jj + 1] + bias[n + 1];
            float c2 = acc[i][jj + 2] + bias[n + 2];
            float c3 = acc[i][jj + 3] + bias[n + 3];
            if (RELU) {
                c0 = fmaxf(c0, 0.f); c1 = fmaxf(c1, 0.f);
                c2 = fmaxf(c2, 0.f); c3 = fmaxf(c3, 0.f);
            }
            c4.x = c0; c4.y = c1; c4.z = c2; c4.w = c3;
            *reinterpret_cast<float4*>(C + m * N + n) = c4;
        }
    }
}

// ---------------------------------------------------------------------------
// Round-6 fused GEMM+LIF (mid-tier only): in-kernel fp32->f16 2-term A split,
// UNSWIZZLED weights/LDS, 1-barrier double-buffered K loop.
// ---------------------------------------------------------------------------
template<bool SPLITX, bool PERM, bool RELU, bool WRITE_LAST, bool F16OUT>
__global__ __launch_bounds__(256, 2)
void gemm_lif(const float* __restrict__ A,
              const f16* __restrict__ Bhi, const f16* __restrict__ Blo,
              const float* __restrict__ bias,
              float* __restrict__ S, float* __restrict__ last_out,
              f16* __restrict__ Sf,
              int N, int K) {
    constexpr int BK = 32;
    constexpr int NBUF = SPLITX ? 4 : 3;
    constexpr int BUFSTR = NBUF * 4096;
    constexpr size_t SMEM = (2 * BUFSTR * 2 > 64 * 132 * 4)
                                ? (size_t)(2 * BUFSTR * 2)
                                : (size_t)(64 * 132 * 4);
    __shared__ __align__(16) char smem[SMEM];
    f16* sm = (f16*)smem;
    float (*Cs)[132] = (float (*)[132])smem;

    const int tid  = threadIdx.x;
    const int lane = tid & 63;
    const int w    = tid >> 6;
    const int wr   = w >> 1, wc = w & 1;
    const int ntile = N >> 7;
    const int bx = blockIdx.x % ntile;
    const int b  = blockIdx.x / ntile;
    const int col0 = bx << 7;

    f32x4 acc0[4][4], acc1[4][4];
#pragma unroll
    for (int mi = 0; mi < 4; ++mi)
#pragma unroll
        for (int ni = 0; ni < 4; ++ni) {
            acc0[mi][ni] = {0.f, 0.f, 0.f, 0.f};
            acc1[mi][ni] = {0.f, 0.f, 0.f, 0.f};
        }

    {
        f16* Ah0 = sm;
        f16* Bh0 = sm + 4096;
        f16* Bl0 = sm + 8192;
        f16* Al0 = sm + 12288;
#pragma unroll
        for (int p = 0; p < 2; ++p) {
            int chunk = w * 2 + p;
            int r  = chunk * 16 + (lane >> 2);
            int kq = lane & 3;
            size_t off = (size_t)(col0 + r) * K + kq * 8;
            gload_lds16(Bhi + off, Bh0 + chunk * 512);
            gload_lds16(Blo + off, Bl0 + chunk * 512);
        }
#pragma unroll
        for (int p = 0; p < 4; ++p) {
            int c = tid + p * 256;
            int r = c >> 3;
            int q = c & 7;
            const float* arow = PERM ? A + (size_t)(b * T_ + r) * K
                                     : A + (size_t)(r * B_ + b) * K;
            float4 v = *reinterpret_cast<const float4*>(arow + q * 4);
            union { f16 h[4]; uint2 u; } hi;
            hi.h[0] = (f16)v.x; hi.h[1] = (f16)v.y;
            hi.h[2] = (f16)v.z; hi.h[3] = (f16)v.w;
            *reinterpret_cast<uint2*>(&Ah0[r * BK + q * 4]) = hi.u;
            if (SPLITX) {
                union { f16 h[4]; uint2 u; } lo;
                lo.h[0] = (f16)((v.x - (float)hi.h[0]) * 4096.0f);
                lo.h[1] = (f16)((v.y - (float)hi.h[1]) * 4096.0f);
                lo.h[2] = (f16)((v.z - (float)hi.h[2]) * 4096.0f);
                lo.h[3] = (f16)((v.w - (float)hi.h[3]) * 4096.0f);
                *reinterpret_cast<uint2*>(&Al0[r * BK + q * 4]) = lo.u;
            }
        }
    }
    __syncthreads();

    const int NIT = K / BK;
    for (int it = 0; it < NIT; ++it) {
        const int cur = it & 1, nxt = cur ^ 1;
        const bool more = (it + 1 < NIT);
        const int k0n = (it + 1) * BK;

        f16* Ah_c = sm + cur * BUFSTR;
        f16* Bh_c = Ah_c + 4096;
        f16* Bl_c = Ah_c + 8192;
        f16* Al_c = Ah_c + 12288;
        f16* Ah_n = sm + nxt * BUFSTR;
        f16* Bh_n = Ah_n + 4096;
        f16* Bl_n = Ah_n + 8192;
        f16* Al_n = Ah_n + 12288;

        float4 a4[4];
        if (more) {
#pragma unroll
            for (int p = 0; p < 2; ++p) {
                int chunk = w * 2 + p;
                int r  = chunk * 16 + (lane >> 2);
                int kq = lane & 3;
                size_t off = (size_t)(col0 + r) * K + k0n + kq * 8;
                gload_lds16(Bhi + off, Bh_n + chunk * 512);
                gload_lds16(Blo + off, Bl_n + chunk * 512);
            }
#pragma unroll
            for (int p = 0; p < 4; ++p) {
                int c = tid + p * 256;
                int r = c >> 3;
                int q = c & 7;
                const float* arow = PERM ? A + (size_t)(b * T_ + r) * K
                                         : A + (size_t)(r * B_ + b) * K;
                a4[p] = *reinterpret_cast<const float4*>(arow + k0n + q * 4);
            }
        }

        {
            f16x8 ahi[4], alo[4];
#pragma unroll
            for (int mi = 0; mi < 4; ++mi) {
                int ar = (wr * 64 + mi * 16 + (lane & 15)) * BK + (lane >> 4) * 8;
                ahi[mi] = *reinterpret_cast<const f16x8*>(&Ah_c[ar]);
                if (SPLITX) alo[mi] = *reinterpret_cast<const f16x8*>(&Al_c[ar]);
            }
#pragma unroll
            for (int ni = 0; ni < 4; ++ni) {
                int br = (wc * 64 + ni * 16 + (lane & 15)) * BK + (lane >> 4) * 8;
                f16x8 bh = *reinterpret_cast<const f16x8*>(&Bh_c[br]);
                f16x8 bl = *reinterpret_cast<const f16x8*>(&Bl_c[br]);
#pragma unroll
                for (int mi = 0; mi < 4; ++mi) {
                    acc0[mi][ni] = __builtin_amdgcn_mfma_f32_16x16x32_f16(
                        ahi[mi], bh, acc0[mi][ni], 0, 0, 0);
                    acc1[mi][ni] = __builtin_amdgcn_mfma_f32_16x16x32_f16(
                        ahi[mi], bl, acc1[mi][ni], 0, 0, 0);
                    if (SPLITX)
                        acc1[mi][ni] = __builtin_amdgcn_mfma_f32_16x16x32_f16(
                            alo[mi], bh, acc1[mi][ni], 0, 0, 0);
                }
            }
        }

        if (more) {
#pragma unroll
            for (int p = 0; p < 4; ++p) {
                int c = tid + p * 256;
                int r = c >> 3;
                int q = c & 7;
                float4 v = a4[p];
                union { f16 h[4]; uint2 u; } hi;
                hi.h[0] = (f16)v.x; hi.h[1] = (f16)v.y;
                hi.h[2] = (f16)v.z; hi.h[3] = (f16)v.w;
                *reinterpret_cast<uint2*>(&Ah_n[r * BK + q * 4]) = hi.u;
                if (SPLITX) {
                    union { f16 h[4]; uint2 u; } lo;
                    lo.h[0] = (f16)((v.x - (float)hi.h[0]) * 4096.0f);
                    lo.h[1] = (f16)((v.y - (float)hi.h[1]) * 4096.0f);
                    lo.h[2] = (f16)((v.z - (float)hi.h[2]) * 4096.0f);
                    lo.h[3] = (f16)((v.w - (float)hi.h[3]) * 4096.0f);
                    *reinterpret_cast<uint2*>(&Al_n[r * BK + q * 4]) = lo.u;
                }
            }
        }
        __syncthreads();
    }

    float v = 0.f, s = 0.f;
    float* Sp = S + (size_t)b * N + col0 + (tid & 127);
    const size_t tstride = (size_t)B_ * N;

    if (wr == 0) {
#pragma unroll
        for (int ni = 0; ni < 4; ++ni) {
            int col = wc * 64 + ni * 16 + (lane & 15);
            float bv = bias[col0 + col];
#pragma unroll
            for (int mi = 0; mi < 4; ++mi) {
                int rowb = mi * 16 + ((lane >> 4) << 2);
#pragma unroll
                for (int r = 0; r < 4; ++r) {
                    float cv = acc0[mi][ni][r] + S12 * acc1[mi][ni][r] + bv;
                    if (RELU) cv = fmaxf(cv, 0.f);
                    Cs[rowb + r][col] = cv;
                }
            }
        }
    }
    __syncthreads();
    if (tid < 128) {
#pragma unroll 4
        for (int t = 0; t < 64; ++t) {
            float in = Cs[t][tid];
            v = v + (in - v) * ALPHA;
            bool sp = (v >= THR);
            s = sp ? 1.0f : 0.0f;
            Sp[(size_t)t * tstride] = s;
            if (F16OUT) Sf[((size_t)b * T_ + t) * N + col0 + tid] = (f16)s;
            v = sp ? 0.0f : v;
        }
    }
    __syncthreads();
    if (wr == 1) {
#pragma unroll
        for (int ni = 0; ni < 4; ++ni) {
            int col = wc * 64 + ni * 16 + (lane & 15);
            float bv = bias[col0 + col];
#pragma unroll
            for (int mi = 0; mi < 4; ++mi) {
                int rowb = mi * 16 + ((lane >> 4) << 2);
#pragma unroll
                for (int r = 0; r < 4; ++r) {
                    float cv = acc0[mi][ni][r] + S12 * acc1[mi][ni][r] + bv;
                    if (RELU) cv = fmaxf(cv, 0.f);
                    Cs[rowb + r][col] = cv;
                }
            }
        }
    }
    __syncthreads();
    if (tid < 128) {
#pragma unroll 4
        for (int t = 64; t < 128; ++t) {
            float in = Cs[t - 64][tid];
            v = v + (in - v) * ALPHA;
            bool sp = (v >= THR);
            s = sp ? 1.0f : 0.0f;
            Sp[(size_t)t * tstride] = s;
            if (F16OUT) Sf[((size_t)b * T_ + t) * N + col0 + tid] = (f16)s;
            v = sp ? 0.0f : v;
        }
        if (WRITE_LAST) last_out[(size_t)b * N + col0 + tid] = s;
    }
}

// ---------------------------------------------------------------------------
// Layer-0 kernel v3: single-buffered A (Ah/Al), double-buffered B -> 48 KB
// LDS -> 3 blocks/CU (was 64 KB / 2 blocks). A is written LATE (after the
// MFMAs read it), so single-buffering costs one extra barrier per K-step:
//   [issue B(next)+A(next)->regs] compute | bar | write A(next) | bar
// Swizzled LDS (weights pre-swizzled, A writes XOR-permuted, swizzled frag
// reads) and the exact 2-term f16 split math — both byte-identical to the
// proven round-10 kernel. Epilogue unchanged.
// ---------------------------------------------------------------------------
__global__ __launch_bounds__(256, 3)
void gemm_lif_x3(const float* __restrict__ A,          // x [B][T][K]
                 const f16* __restrict__ Bhi,          // [N][K] pre-swizzled
                 const f16* __restrict__ Blo,          // [N][K] pre-swizzled
                 const float* __restrict__ bias,
                 float* __restrict__ S,                // [T][B][N] fp32 spikes
                 f16* __restrict__ Sf,                 // [B][T][N] f16 spikes
                 int N, int K) {
    constexpr int BK = 32;
    // LDS: Ah[4096] Al[4096] (single) | 2 x (Bh[4096] Bl[4096]) = 24576 f16
    __shared__ __align__(16) char smem[49152];         // 48 KB >= Cs 33792
    f16* sm = (f16*)smem;
    f16* Ah = sm;
    f16* Al = sm + 4096;
    float (*Cs)[132] = (float (*)[132])smem;

    const int tid  = threadIdx.x;
    const int lane = tid & 63;
    const int w    = tid >> 6;
    const int wr   = w >> 1, wc = w & 1;
    const int ntile = N >> 7;
    const int bx = blockIdx.x % ntile;
    const int b  = blockIdx.x / ntile;
    const int col0 = bx << 7;
    const int sw = (((lane >> 4) ^ ((lane >> 1) & 3)) << 3);

    f32x4 acc0[4][4], acc1[4][4];
#pragma unroll
    for (int mi = 0; mi < 4; ++mi)
#pragma unroll
        for (int ni = 0; ni < 4; ++ni) {
            acc0[mi][ni] = {0.f, 0.f, 0.f, 0.f};
            acc1[mi][ni] = {0.f, 0.f, 0.f, 0.f};
        }

    // prologue: stage B(0) into buf 0; A(0) via regs -> Ah/Al (swizzled)
    {
        f16* Bh0 = sm + 8192;
        f16* Bl0 = sm + 12288;
#pragma unroll
        for (int p = 0; p < 2; ++p) {
            int chunk = w * 2 + p;
            int r  = chunk * 16 + (lane >> 2);
            int kq = lane & 3;
            size_t off = (size_t)(col0 + r) * K + kq * 8;
            gload_lds16(Bhi + off, Bh0 + chunk * 512);
            gload_lds16(Blo + off, Bl0 + chunk * 512);
        }
#pragma unroll
        for (int p = 0; p < 4; ++p) {
            int c = tid + p * 256;
            int r = c >> 3;
            int q = c & 7;
            const float* arow = A + (size_t)(b * T_ + r) * K;
            float4 v = *reinterpret_cast<const float4*>(arow + q * 4);
            int aoff = r * 32 + ((((q >> 1) ^ ((r >> 1) & 3))) << 3) + ((q & 1) << 2);
            union { f16 h[4]; uint2 u; } hi;
            hi.h[0] = (f16)v.x; hi.h[1] = (f16)v.y;
            hi.h[2] = (f16)v.z; hi.h[3] = (f16)v.w;
            *reinterpret_cast<uint2*>(&Ah[aoff]) = hi.u;
            union { f16 h[4]; uint2 u; } lo;
            lo.h[0] = (f16)((v.x - (float)hi.h[0]) * 4096.0f);
            lo.h[1] = (f16)((v.y - (float)hi.h[1]) * 4096.0f);
            lo.h[2] = (f16)((v.z - (float)hi.h[2]) * 4096.0f);
            lo.h[3] = (f16)((v.w - (float)hi.h[3]) * 4096.0f);
            *reinterpret_cast<uint2*>(&Al[aoff]) = lo.u;
        }
    }
    __syncthreads();

    const int NIT = K / BK;
    for (int it = 0; it < NIT; ++it) {
        const bool more = (it + 1 < NIT);
        const int k0n = (it + 1) * BK;
        f16* Bh_c = sm + 8192 + (it & 1) * 8192;
        f16* Bl_c = Bh_c + 4096;

        // issue next tile's loads (B -> other LDS buf, A -> registers)
        float4 a4[4];
        if (more) {
            f16* Bh_n = sm + 8192 + ((it + 1) & 1) * 8192;
            f16* Bl_n = Bh_n + 4096;
#pragma unroll
            for (int p = 0; p < 2; ++p) {
                int chunk = w * 2 + p;
                int r  = chunk * 16 + (lane >> 2);
                int kq = lane & 3;
                size_t off = (size_t)(col0 + r) * K + k0n + kq * 8;
                gload_lds16(Bhi + off, Bh_n + chunk * 512);
                gload_lds16(Blo + off, Bl_n + chunk * 512);
            }
#pragma unroll
            for (int p = 0; p < 4; ++p) {
                int c = tid + p * 256;
                int r = c >> 3;
                int q = c & 7;
                const float* arow = A + (size_t)(b * T_ + r) * K;
                a4[p] = *reinterpret_cast<const float4*>(arow + k0n + q * 4);
            }
        }

        // compute on single A buffer + current B buffer
        {
            f16x8 ahi[4], alo[4];
#pragma unroll
            for (int mi = 0; mi < 4; ++mi) {
                int ar = (wr * 64 + mi * 16 + (lane & 15)) * BK + sw;
                ahi[mi] = *reinterpret_cast<const f16x8*>(&Ah[ar]);
                alo[mi] = *reinterpret_cast<const f16x8*>(&Al[ar]);
            }
#pragma unroll
            for (int ni = 0; ni < 4; ++ni) {
                int br = (wc * 64 + ni * 16 + (lane & 15)) * BK + sw;
                f16x8 bh = *reinterpret_cast<const f16x8*>(&Bh_c[br]);
                f16x8 bl = *reinterpret_cast<const f16x8*>(&Bl_c[br]);
#pragma unroll
                for (int mi = 0; mi < 4; ++mi) {
                    acc0[mi][ni] = __builtin_amdgcn_mfma_f32_16x16x32_f16(
                        ahi[mi], bh, acc0[mi][ni], 0, 0, 0);
                    acc1[mi][ni] = __builtin_amdgcn_mfma_f32_16x16x32_f16(
                        ahi[mi], bl, acc1[mi][ni], 0, 0, 0);
                    acc1[mi][ni] = __builtin_amdgcn_mfma_f32_16x16x32_f16(
                        alo[mi], bh, acc1[mi][ni], 0, 0, 0);
                }
            }
        }
        __syncthreads();   // all waves done READING Ah/Al

        // late write: A(next) into the SAME buffers
        if (more) {
#pragma unroll
            for (int p = 0; p < 4; ++p) {
                int c = tid + p * 256;
                int r = c >> 3;
                int q = c & 7;
                float4 v = a4[p];
                int aoff = r * 32 + ((((q >> 1) ^ ((r >> 1) & 3))) << 3) + ((q & 1) << 2);
                union { f16 h[4]; uint2 u; } hi;
                hi.h[0] = (f16)v.x; hi.h[1] = (f16)v.y;
                hi.h[2] = (f16)v.z; hi.h[3] = (f16)v.w;
                *reinterpret_cast<uint2*>(&Ah[aoff]) = hi.u;
                union { f16 h[4]; uint2 u; } lo;
                lo.h[0] = (f16)((v.x - (float)hi.h[0]) * 4096.0f);
                lo.h[1] = (f16)((v.y - (float)hi.h[1]) * 4096.0f);
                lo.h[2] = (f16)((v.z - (float)hi.h[2]) * 4096.0f);
                lo.h[3] = (f16)((v.w - (float)hi.h[3]) * 4096.0f);
                *reinterpret_cast<uint2*>(&Al[aoff]) = lo.u;
            }
        }
        __syncthreads();   // A(next) visible; B(next) drained by barrier
    }

    // two-phase epilogue: RELU + LIF + fp32 spikes + f16 mirror
    float v = 0.f;
    float* Sp = S + (size_t)b * N + col0 + (tid & 127);
    const size_t tstride = (size_t)B_ * N;

    if (wr == 0) {
#pragma unroll
        for (int ni = 0; ni < 4; ++ni) {
            int col = wc * 64 + ni * 16 + (lane & 15);
            float bv = bias[col0 + col];
#pragma unroll
            for (int mi = 0; mi < 4; ++mi) {
                int rowb = mi * 16 + ((lane >> 4) << 2);
#pragma unroll
                for (int r = 0; r < 4; ++r) {
                    float cv = fmaxf(acc0[mi][ni][r] + S12 * acc1[mi][ni][r] + bv, 0.f);
                    Cs[rowb + r][col] = cv;
                }
            }
        }
    }
    __syncthreads();
    if (tid < 128) {
#pragma unroll 4
        for (int t = 0; t < 64; ++t) {
            float in = Cs[t][tid];
            v = v + (in - v) * ALPHA;
            bool sp = (v >= THR);
            float s = sp ? 1.0f : 0.0f;
            Sp[(size_t)t * tstride] = s;
            Sf[((size_t)b * T_ + t) * N + col0 + tid] = (f16)s;
            v = sp ? 0.0f : v;
        }
    }
    __syncthreads();
    if (wr == 1) {
#pragma unroll
        for (int ni = 0; ni < 4; ++ni) {
            int col = wc * 64 + ni * 16 + (lane & 15);
            float bv = bias[col0 + col];
#pragma unroll
            for (int mi = 0; mi < 4; ++mi) {
                int rowb = mi * 16 + ((lane >> 4) << 2);
#pragma unroll
                for (int r = 0; r < 4; ++r) {
                    float cv = fmaxf(acc0[mi][ni][r] + S12 * acc1[mi][ni][r] + bv, 0.f);
                    Cs[rowb + r][col] = cv;
                }
            }
        }
    }
    __syncthreads();
    if (tid < 128) {
#pragma unroll 4
        for (int t = 64; t < 128; ++t) {
            float in = Cs[t - 64][tid];
            v = v + (in - v) * ALPHA;
            bool sp = (v >= THR);
            float s = sp ? 1.0f : 0.0f;
            Sp[(size_t)t * tstride] = s;
            Sf[((size_t)b * T_ + t) * N + col0 + tid] = (f16)s;
            v = sp ? 0.0f : v;
        }
    }
}

// ---------------------------------------------------------------------------
// f16-A consumer (L1/L2): A rows [B][T][K] f16, staged via global_load_lds
// like B; NO in-loop conversion VALU. Weights pre-swizzled; A source-side
// swizzled to match. 1-barrier double-buffered K loop; 48 KB -> 3 blocks/CU.
// ---------------------------------------------------------------------------
template<bool WRITE_LAST, bool F16OUT>
__global__ __launch_bounds__(256, 3)
void gemm_lif_h(const f16* __restrict__ Af,     // [B][T][K] f16 spikes
                const f16* __restrict__ Bhi,    // [N][K] pre-swizzled
                const f16* __restrict__ Blo,    // [N][K] pre-swizzled (x 2^12)
                const float* __restrict__ bias,
                float* __restrict__ S,          // [T][B][N] fp32 spikes
                float* __restrict__ last_out,   // [B][N] (WRITE_LAST)
                f16* __restrict__ Sf,           // [B][T][N] f16 spikes (F16OUT)
                int N, int K) {
    constexpr int BK = 32;
    constexpr int BUFF = 3 * 4096;              // f16 elems: Ah, Bh, Bl
    __shared__ __align__(16) char smem[2 * BUFF * 2];   // 48 KB >= Cs 33792
    f16* sm = (f16*)smem;
    float (*Cs)[132] = (float (*)[132])smem;

    const int tid  = threadIdx.x;
    const int lane = tid & 63;
    const int w    = tid >> 6;
    const int wr   = w >> 1, wc = w & 1;
    const int ntile = N >> 7;
    const int bx = blockIdx.x % ntile;
    const int b  = blockIdx.x / ntile;
    const int col0 = bx << 7;
    const int sw = (((lane >> 4) ^ ((lane >> 1) & 3)) << 3);

    f32x4 acc0[4][4], acc1[4][4];
#pragma unroll
    for (int mi = 0; mi < 4; ++mi)
#pragma unroll
        for (int ni = 0; ni < 4; ++ni) {
            acc0[mi][ni] = {0.f, 0.f, 0.f, 0.f};
            acc1[mi][ni] = {0.f, 0.f, 0.f, 0.f};
        }

    // staging addresses (per lane)
    const int r0   = (w * 2 + 0) * 16 + (lane >> 2);
    const int r1   = (w * 2 + 1) * 16 + (lane >> 2);
    const int kqs  = lane & 3;
    const int kqa0 = kqs ^ ((r0 >> 1) & 3);
    const int kqa1 = kqs ^ ((r1 >> 1) & 3);

    // prologue: stage tile 0 into buffer 0
    {
        size_t b0 = (size_t)(col0 + r0) * K + kqs * 8;
        size_t b1 = (size_t)(col0 + r1) * K + kqs * 8;
        size_t a0 = ((size_t)b * T_ + r0) * K + kqa0 * 8;
        size_t a1 = ((size_t)b * T_ + r1) * K + kqa1 * 8;
        gload_lds16(Af + a0,  sm + (w * 2 + 0) * 512);
        gload_lds16(Af + a1,  sm + (w * 2 + 1) * 512);
        gload_lds16(Bhi + b0, sm + 4096 + (w * 2 + 0) * 512);
        gload_lds16(Bhi + b1, sm + 4096 + (w * 2 + 1) * 512);
        gload_lds16(Blo + b0, sm + 8192 + (w * 2 + 0) * 512);
        gload_lds16(Blo + b1, sm + 8192 + (w * 2 + 1) * 512);
    }
    __syncthreads();

    const int NIT = K / BK;
    for (int it = 0; it < NIT; ++it) {
        f16* cur = sm + (it & 1) * BUFF;
        if (it + 1 < NIT) {
            f16* nb = sm + ((it + 1) & 1) * BUFF;
            int k0n = (it + 1) * BK;
            size_t b0 = (size_t)(col0 + r0) * K + k0n + kqs * 8;
            size_t b1 = (size_t)(col0 + r1) * K + k0n + kqs * 8;
            size_t a0 = ((size_t)b * T_ + r0) * K + k0n + kqa0 * 8;
            size_t a1 = ((size_t)b * T_ + r1) * K + k0n + kqa1 * 8;
            gload_lds16(Af + a0,  nb + (w * 2 + 0) * 512);
            gload_lds16(Af + a1,  nb + (w * 2 + 1) * 512);
            gload_lds16(Bhi + b0, nb + 4096 + (w * 2 + 0) * 512);
            gload_lds16(Bhi + b1, nb + 4096 + (w * 2 + 1) * 512);
            gload_lds16(Blo + b0, nb + 8192 + (w * 2 + 0) * 512);
            gload_lds16(Blo + b1, nb + 8192 + (w * 2 + 1) * 512);
        }

        f16x8 af[4];
#pragma unroll
        for (int mi = 0; mi < 4; ++mi)
            af[mi] = *reinterpret_cast<const f16x8*>(
                &cur[(wr * 64 + mi * 16 + (lane & 15)) * BK + sw]);
#pragma unroll
        for (int ni = 0; ni < 4; ++ni) {
            int br = (wc * 64 + ni * 16 + (lane & 15)) * BK + sw;
            f16x8 bh = *reinterpret_cast<const f16x8*>(&cur[4096 + br]);
            f16x8 bl = *reinterpret_cast<const f16x8*>(&cur[8192 + br]);
#pragma unroll
            for (int mi = 0; mi < 4; ++mi) {
                acc0[mi][ni] = __builtin_amdgcn_mfma_f32_16x16x32_f16(
                    af[mi], bh, acc0[mi][ni], 0, 0, 0);
                acc1[mi][ni] = __builtin_amdgcn_mfma_f32_16x16x32_f16(
                    af[mi], bl, acc1[mi][ni], 0, 0, 0);
            }
        }
        __syncthreads();
    }

    // two-phase epilogue: transpose halves through Cs + LIF scan
    float v = 0.f, s = 0.f;
    float* Sp = S + (size_t)b * N + col0 + (tid & 127);
    const size_t tstride = (size_t)B_ * N;

    if (wr == 0) {
#pragma unroll
        for (int ni = 0; ni < 4; ++ni) {
            int col = wc * 64 + ni * 16 + (lane & 15);
            float bv = bias[col0 + col];
#pragma unroll
            for (int mi = 0; mi < 4; ++mi) {
                int rowb = mi * 16 + ((lane >> 4) << 2);
#pragma unroll
                for (int r = 0; r < 4; ++r)
                    Cs[rowb + r][col] = acc0[mi][ni][r] + S12 * acc1[mi][ni][r] + bv;
            }
        }
    }
    __syncthreads();
    if (tid < 128) {
#pragma unroll 4
        for (int t = 0; t < 64; ++t) {
            float in = Cs[t][tid];
            v = v + (in - v) * ALPHA;
            bool sp = (v >= THR);
            s = sp ? 1.0f : 0.0f;
            Sp[(size_t)t * tstride] = s;
            if (F16OUT) Sf[((size_t)b * T_ + t) * N + col0 + tid] = (f16)s;
            v = sp ? 0.0f : v;
        }
    }
    __syncthreads();
    if (wr == 1) {
#pragma unroll
        for (int ni = 0; ni < 4; ++ni) {
            int col = wc * 64 + ni * 16 + (lane & 15);
            float bv = bias[col0 + col];
#pragma unroll
            for (int mi = 0; mi < 4; ++mi) {
                int rowb = mi * 16 + ((lane >> 4) << 2);
#pragma unroll
                for (int r = 0; r < 4; ++r)
                    Cs[rowb + r][col] = acc0[mi][ni][r] + S12 * acc1[mi][ni][r] + bv;
            }
        }
    }
    __syncthreads();
    if (tid < 128) {
#pragma unroll 4
        for (int t = 64; t < 128; ++t) {
            float in = Cs[t - 64][tid];
            v = v + (in - v) * ALPHA;
            bool sp = (v >= THR);
            s = sp ? 1.0f : 0.0f;
            Sp[(size_t)t * tstride] = s;
            if (F16OUT) Sf[((size_t)b * T_ + t) * N + col0 + tid] = (f16)s;
            v = sp ? 0.0f : v;
        }
        if (WRITE_LAST) last_out[(size_t)b * N + col0 + tid] = s;
    }
}

// ---------------------------------------------------------------------------
// LIF time-scan (fp32 fallback path)
// ---------------------------------------------------------------------------
__global__ __launch_bounds__(256)
void lif_scan(float* __restrict__ buf, int BH, float* __restrict__ last_out) {
    int j = blockIdx.x * 256 + threadIdx.x;
    if (j >= BH) return;
    float v = 0.f;
    float last = 0.f;
    for (int t = 0; t < T_; ++t) {
        size_t idx = (size_t)t * BH + j;
        float in = buf[idx];
        v = v + (in - v) * ALPHA;
        bool sp = (v >= THR);
        last = sp ? 1.0f : 0.0f;
        buf[idx] = last;
        v = sp ? 0.0f : v;
    }
    if (last_out) last_out[j] = last;
}

// ---------------------------------------------------------------------------
// Tiled f64-accumulation fold: Wf[h][o] = sum_k W2[h][k]*Wo[k][o]  (fp32 out)
// ---------------------------------------------------------------------------
__global__ __launch_bounds__(256)
void make_wf2(const float* __restrict__ W2, const float* __restrict__ Wo,
              float* __restrict__ Wf) {
    __shared__ float w2s[64][33];
    __shared__ float wos[64][68];
    const int tid = threadIdx.x;
    const int ht = blockIdx.x >> 3, ot = blockIdx.x & 7;
    const int h0 = ht * 32, o0 = ot * 64;
    const int th = tid >> 3;
    const int to = tid & 7;

    double acc[8] = {0, 0, 0, 0, 0, 0, 0, 0};

    for (int k0 = 0; k0 < H_; k0 += 64) {
#pragma unroll
        for (int p = 0; p < 2; ++p) {
            int f = tid + p * 256;
            int i = f >> 4;
            int j4 = (f & 15) << 2;
            float4 v = *reinterpret_cast<const float4*>(
                W2 + (size_t)(h0 + i) * H_ + k0 + j4);
            w2s[j4 + 0][i] = v.x; w2s[j4 + 1][i] = v.y;
            w2s[j4 + 2][i] = v.z; w2s[j4 + 3][i] = v.w;
        }
#pragma unroll
        for (int p = 0; p < 4; ++p) {
            int f = tid + p * 256;
            int r = f >> 4;
            int c4 = (f & 15) << 2;
            float4 v = *reinterpret_cast<const float4*>(
                Wo + (size_t)(k0 + r) * O_ + o0 + c4);
            wos[r][c4 + 0] = v.x; wos[r][c4 + 1] = v.y;
            wos[r][c4 + 2] = v.z; wos[r][c4 + 3] = v.w;
        }
        __syncthreads();

#pragma unroll 8
        for (int k = 0; k < 64; ++k) {
            double a = (double)w2s[k][th];
#pragma unroll
            for (int j = 0; j < 8; ++j)
                acc[j] += a * (double)wos[k][to * 8 + j];
        }
        __syncthreads();
    }
#pragma unroll
    for (int j = 0; j < 8; ++j)
        Wf[(size_t)(h0 + th) * O_ + o0 + to * 8 + j] = (float)acc[j];
}

// bf[o] = bo[o] + sum_h b2[h]*Wo[h][o]  (f64 accum, serial; mid/fallback)
__global__ __launch_bounds__(256)
void make_bf(const float* __restrict__ Wo, const float* __restrict__ b2,
             const float* __restrict__ bo, float* __restrict__ bf) {
    int o = blockIdx.x * 256 + threadIdx.x;
    if (o >= O_) return;
    double acc = (double)bo[o];
    for (int h = 0; h < H_; ++h)
        acc += (double)b2[h] * (double)Wo[(size_t)h * O_ + o];
    bf[o] = (float)acc;
}

// Parallel make_bf (hi-tier): 8 blocks x 256 threads, 4-way h-partition +
// f64 tree reduce. Coalesced Wo reads. f64 partial-sum order change rounds
// to the same f32 result.
__global__ __launch_bounds__(256)
void make_bf2(const float* __restrict__ Wo, const float* __restrict__ b2,
              const float* __restrict__ bo, float* __restrict__ bf) {
    __shared__ double red[4][64];
    const int tid  = threadIdx.x;
    const int ol   = tid & 63;
    const int part = tid >> 6;                  // 0..3
    const int o    = blockIdx.x * 64 + ol;      // grid = O_/64 = 8
    double acc = 0.0;
    for (int h = part; h < H_; h += 4)
        acc += (double)b2[h] * (double)Wo[(size_t)h * O_ + o];
    red[part][ol] = acc;
    __syncthreads();
    if (part == 0) {
        double s = red[0][ol] + red[1][ol] + red[2][ol] + red[3][ol];
        bf[o] = (float)((double)bo[o] + s);
    }
}

// 2-term scaled fp16 split of W [K][N], TRANSPOSED [N][K] (mid-tier version;
// strided reads).
template<bool SWZ>
__global__ __launch_bounds__(256)
void split_w16(const float* __restrict__ W, f16* __restrict__ hi,
               f16* __restrict__ lo, int K, int N) {
    int idx = blockIdx.x * 256 + threadIdx.x;     // idx = n*K + k_stored
    if (idx >= K * N) return;
    int n = idx / K;
    int ks = idx - n * K;
    int k = SWZ ? ((ks & ~31) | ((((ks >> 3) & 3) ^ ((n >> 1) & 3)) << 3) | (ks & 7))
                : ks;
    float wv = W[(size_t)k * N + n];
    f16 h0 = (f16)wv;
    float r = (wv - (float)h0) * 4096.0f;
    f16 h1 = (f16)r;
    hi[idx] = h0; lo[idx] = h1;
}

// Coalesced transpose-split (hi-tier): 64x64 f32 tile through LDS; reads and
// writes both coalesced. Per-element math identical to split_w16. K,N must
// be multiples of 64 (true for all three weight matrices).
template<bool SWZ>
__global__ __launch_bounds__(256)
void split_w16t(const float* __restrict__ W, f16* __restrict__ hi,
                f16* __restrict__ lo, int K, int N) {
    __shared__ float tile[64][65];
    const int tid = threadIdx.x;
    const int ntile = N >> 6;
    const int kt = blockIdx.x / ntile;
    const int nt = blockIdx.x % ntile;
    const int k0 = kt << 6, n0 = nt << 6;

    // load 64x64 tile, coalesced along n
#pragma unroll
    for (int p = 0; p < 4; ++p) {
        int lin = p * 256 + tid;          // 0..1023 float4 chunks
        int r = lin >> 4;                 // 0..63 (k row)
        int c = (lin & 15) << 2;          // 0..60 (n col)
        float4 v = *reinterpret_cast<const float4*>(
            W + (size_t)(k0 + r) * N + n0 + c);
        tile[r][c + 0] = v.x; tile[r][c + 1] = v.y;
        tile[r][c + 2] = v.z; tile[r][c + 3] = v.w;
    }
    __syncthreads();

    // write: thread -> one n row, 16 consecutive stored-k (two ushort8 stores)
    const int nl = tid >> 2;              // 0..63
    const int q  = tid & 3;               // 0..3 (16-k quad)
    const int n  = n0 + nl;
#pragma unroll
    for (int half = 0; half < 2; ++half) {
        union { f16 h[8]; uint4 u4; } Hh, Hl;
#pragma unroll
        for (int j = 0; j < 8; ++j) {
            int ksl = q * 16 + half * 8 + j;          // stored k, local
            int kl  = SWZ ? ((ksl & ~31) |
                             ((((ksl >> 3) & 3) ^ ((n >> 1) & 3)) << 3) |
                             (ksl & 7))
                          : ksl;                       // source k, local
            float wv = tile[kl][nl];
            f16 h0 = (f16)wv;
            float rr = (wv - (float)h0) * 4096.0f;
            Hh.h[j] = h0; Hl.h[j] = (f16)rr;
        }
        size_t off = (size_t)n * K + k0 + q * 16 + half * 8;
        *reinterpret_cast<uint4*>(hi + off) = Hh.u4;
        *reinterpret_cast<uint4*>(lo + off) = Hl.u4;
    }
}

// ---------------------------------------------------------------------------
extern "C" void kernel_launch(void* const* d_in, const int* in_sizes, int n_in,
                              void* d_out, int out_size, void* d_ws, size_t ws_size,
                              hipStream_t stream) {
    const float* x  = (const float*)d_in[0];
    const float* We = (const float*)d_in[1];
    const float* be = (const float*)d_in[2];
    const float* W1 = (const float*)d_in[3];
    const float* b1 = (const float*)d_in[4];
    const float* W2 = (const float*)d_in[5];
    const float* b2 = (const float*)d_in[6];
    const float* Wo = (const float*)d_in[7];
    const float* bo = (const float*)d_in[8];

    float* out = (float*)d_out;
    float* so_last = out;                              // [B, O]
    float* S1 = out + (size_t)B_ * O_;                 // [T, B, H]
    float* S2 = S1 + (size_t)T_ * B_ * H_;             // [T, B, H]
    float* SO = S2 + (size_t)T_ * B_ * H_;             // [T, B, O]

    const int TB = T_ * B_;
    dim3 blk(256);

    const size_t MB = 1024 * 1024;
    const size_t sz_s1f = (size_t)T_ * B_ * H_ * 2;    // 64 MiB

    // ---- hi-tier layout (~144.7 MiB) ----
    const size_t b_weh = 0;                  // 1 MB (swizzled)
    const size_t b_wel = 1 * MB;
    const size_t b_w1h = 2 * MB;             // 2 MB swizzled
    const size_t b_w1l = 4 * MB;
    const size_t b_wfh = 6 * MB;             // 1 MB swizzled
    const size_t b_wfl = 7 * MB;
    const size_t b_bf  = 8 * MB;
    const size_t b_wf  = 8 * MB + 4096;
    const size_t b_s1f = 10 * MB + 4096;
    const size_t b_s2f = b_s1f + sz_s1f;
    const size_t need_hi = b_s2f + sz_s1f;

    // ---- mid-tier (round-6) layout (~10.1 MiB) ----
    const size_t m_weh = 0;
    const size_t m_wel = m_weh + (size_t)I_ * H_ * 2;
    const size_t m_w1h = m_wel + (size_t)I_ * H_ * 2;
    const size_t m_w1l = m_w1h + (size_t)H_ * H_ * 2;
    const size_t m_wf  = m_w1l + (size_t)H_ * H_ * 2;
    const size_t m_bf  = m_wf + (size_t)H_ * O_ * 4;
    const size_t m_wfh = m_bf + (size_t)O_ * 4;
    const size_t m_wfl = m_wfh + (size_t)H_ * O_ * 2;
    const size_t need_mid = m_wfl + (size_t)H_ * O_ * 2;

    if (ws_size >= need_hi) {
        char* ws = (char*)d_ws;
        f16*   weh = (f16*)(ws + b_weh);
        f16*   wel = (f16*)(ws + b_wel);
        f16*   w1h = (f16*)(ws + b_w1h);
        f16*   w1l = (f16*)(ws + b_w1l);
        f16*   wfh = (f16*)(ws + b_wfh);
        f16*   wfl = (f16*)(ws + b_wfl);
        float* bf  = (float*)(ws + b_bf);
        float* Wf  = (float*)(ws + b_wf);
        f16*   s1f = (f16*)(ws + b_s1f);
        f16*   s2f = (f16*)(ws + b_s2f);

        // ---- prep (deterministic, every call; coalesced variants) ----
        split_w16t<true><<<dim3((I_ >> 6) * (H_ >> 6)), blk, 0, stream>>>(We, weh, wel, I_, H_);
        split_w16t<true><<<dim3((H_ >> 6) * (H_ >> 6)), blk, 0, stream>>>(W1, w1h, w1l, H_, H_);
        make_wf2<<<dim3(256), blk, 0, stream>>>(W2, Wo, Wf);
        make_bf2<<<dim3(O_ / 64), blk, 0, stream>>>(Wo, b2, bo, bf);
        split_w16t<true><<<dim3((H_ >> 6) * (O_ >> 6)), blk, 0, stream>>>(Wf, wfh, wfl, H_, O_);

        // ---- Layer 0: S1 + s1f = LIF(relu(x @ We + be))  (48 KB LDS, 3/CU) ----
        gemm_lif_x3<<<dim3(B_ * (H_ / 128)), blk, 0, stream>>>(
            x, weh, wel, be, S1, s1f, H_, I_);

        // ---- Layer 1: S2 + s2f = LIF(s1f @ W1 + b1)  (pure f16-A) ----
        gemm_lif_h<false, true><<<dim3(B_ * (H_ / 128)), blk, 0, stream>>>(
            s1f, w1h, w1l, b1, S2, nullptr, s2f, H_, H_);

        // ---- Layer 2: SO = LIF(s2f @ (W2@Wo) + bf), so_last ----
        gemm_lif_h<true, false><<<dim3(B_ * (O_ / 128)), blk, 0, stream>>>(
            s2f, wfh, wfl, bf, SO, so_last, nullptr, O_, H_);
    } else if (ws_size >= need_mid) {
        // ---- mid-tier: round-6 proven path ----
        char* ws = (char*)d_ws;
        f16*   weh = (f16*)(ws + m_weh);
        f16*   wel = (f16*)(ws + m_wel);
        f16*   w1h = (f16*)(ws + m_w1h);
        f16*   w1l = (f16*)(ws + m_w1l);
        float* Wf  = (float*)(ws + m_wf);
        float* bf  = (float*)(ws + m_bf);
        f16*   wfh = (f16*)(ws + m_wfh);
        f16*   wfl = (f16*)(ws + m_wfl);

        split_w16<false><<<dim3((I_ * H_ + 255) / 256), blk, 0, stream>>>(We, weh, wel, I_, H_);
        split_w16<false><<<dim3((H_ * H_ + 255) / 256), blk, 0, stream>>>(W1, w1h, w1l, H_, H_);
        make_wf2<<<dim3(256), blk, 0, stream>>>(W2, Wo, Wf);
        make_bf<<<dim3(2), blk, 0, stream>>>(Wo, b2, bo, bf);
        split_w16<false><<<dim3((H_ * O_ + 255) / 256), blk, 0, stream>>>(Wf, wfh, wfl, H_, O_);

        gemm_lif<true, true, true, false, false><<<dim3(B_ * (H_ / 128)), blk, 0, stream>>>(
            x, weh, wel, be, S1, nullptr, nullptr, H_, I_);
        gemm_lif<false, false, false, false, false><<<dim3(B_ * (H_ / 128)), blk, 0, stream>>>(
            S1, w1h, w1l, b1, S2, nullptr, nullptr, H_, H_);
        gemm_lif<false, false, false, true, false><<<dim3(B_ * (O_ / 128)), blk, 0, stream>>>(
            S2, wfh, wfl, bf, SO, so_last, nullptr, O_, H_);
    } else {
        // ---- deep fallback: fp32 folded path (~2.1 MB ws) ----
        float* Wf = (float*)d_ws;
        float* bf = Wf + (size_t)H_ * O_;
        gemm128<true, true><<<dim3((TB / 128) * (H_ / 128)), blk, 0, stream>>>(
            x, We, be, S1, TB, H_, I_);
        lif_scan<<<dim3((B_ * H_ + 255) / 256), blk, 0, stream>>>(S1, B_ * H_, nullptr);
        gemm128<false, false><<<dim3((TB / 128) * (H_ / 128)), blk, 0, stream>>>(
            S1, W1, b1, S2, TB, H_, H_);
        lif_scan<<<dim3((B_ * H_ + 255) / 256), blk, 0, stream>>>(S2, B_ * H_, nullptr);
        make_wf2<<<dim3(256), blk, 0, stream>>>(W2, Wo, Wf);
        make_bf<<<dim3(2), blk, 0, stream>>>(Wo, b2, bo, bf);
        gemm128<false, false><<<dim3((TB / 128) * (O_ / 128)), blk, 0, stream>>>(
            S2, Wf, bf, SO, TB, O_, H_);
        lif_scan<<<dim3((B_ * O_ + 255) / 256), blk, 0, stream>>>(SO, B_ * O_, so_last);
    }
}

// Round 12
// 556.159 us; speedup vs baseline: 1.5908x; 1.5908x over previous
//
#include <hip/hip_runtime.h>
#include <cstdint>
#include <cstddef>

// Problem constants (match reference)
#define B_ 256
#define T_ 128
#define I_ 512
#define H_ 1024
#define O_ 512
static constexpr float ALPHA = 1.0f / 20.0f;   // DT/TAU
static constexpr float THR   = 1.0f;
static constexpr float S12   = 0.000244140625f; // 2^-12 (exact)

typedef _Float16 f16;
typedef __attribute__((ext_vector_type(8))) _Float16 f16x8;
typedef __attribute__((ext_vector_type(4))) float f32x4;

__device__ inline void gload_lds16(const void* gsrc, void* ldsdst) {
    __builtin_amdgcn_global_load_lds(
        (const __attribute__((address_space(1))) unsigned int*)gsrc,
        (__attribute__((address_space(3))) unsigned int*)ldsdst, 16, 0, 0);
}

// ---------------------------------------------------------------------------
// fp32 tiled GEMM (deep-fallback path only)
// ---------------------------------------------------------------------------
template<bool PERM_X, bool RELU>
__global__ __launch_bounds__(256)
void gemm128(const float* __restrict__ A, const float* __restrict__ Bw,
             const float* __restrict__ bias, float* __restrict__ C,
             int M, int N, int K) {
    constexpr int BM = 128, BN = 128, BK = 16, TM = 8, TN = 8;
    __shared__ float As[BK][BM];
    __shared__ float Bs[BK][BN + 4];

    const int tid = threadIdx.x;
    const int ntile = N / BN;
    const int bx = blockIdx.x % ntile;
    const int by = blockIdx.x / ntile;
    const int row0 = by * BM, col0 = bx * BN;
    const int tx = tid & 15;
    const int ty = tid >> 4;

    float acc[TM][TN] = {};

    for (int k0 = 0; k0 < K; k0 += BK) {
#pragma unroll
        for (int p = 0; p < 2; ++p) {
            int f = tid + p * 256;
            int r  = f >> 2;
            int kc = (f & 3) << 2;
            int m = row0 + r;
            const float* arow;
            if (PERM_X) {
                int t = m >> 8;
                int b = m & 255;
                arow = A + (size_t)(b * T_ + t) * K;
            } else {
                arow = A + (size_t)m * K;
            }
            float4 v = *reinterpret_cast<const float4*>(arow + k0 + kc);
            As[kc + 0][r] = v.x;
            As[kc + 1][r] = v.y;
            As[kc + 2][r] = v.z;
            As[kc + 3][r] = v.w;
        }
#pragma unroll
        for (int p = 0; p < 2; ++p) {
            int f = tid + p * 256;
            int r  = f >> 5;
            int nc = (f & 31) << 2;
            float4 v = *reinterpret_cast<const float4*>(Bw + (size_t)(k0 + r) * N + col0 + nc);
            *reinterpret_cast<float4*>(&Bs[r][nc]) = v;
        }
        __syncthreads();

#pragma unroll
        for (int k = 0; k < BK; ++k) {
            float a[TM], b[TN];
#pragma unroll
            for (int i = 0; i < TM; ++i) a[i] = As[k][ty * TM + i];
#pragma unroll
            for (int j = 0; j < TN; ++j) b[j] = Bs[k][tx * TN + j];
#pragma unroll
            for (int i = 0; i < TM; ++i)
#pragma unroll
                for (int j = 0; j < TN; ++j)
                    acc[i][j] += a[i] * b[j];
        }
        __syncthreads();
    }

#pragma unroll
    for (int i = 0; i < TM; ++i) {
        size_t m = (size_t)(row0 + ty * TM + i);
#pragma unroll
        for (int jj = 0; jj < TN; jj += 4) {
            int n = col0 + tx * TN + jj;
            float4 c4;
            float c0 = acc[i][jj + 0] + bias[n + 0];
            float c1 = acc[i][jj + 1] + bias[n + 1];
            float c2 = acc[i][jj + 2] + bias[n + 2];
            float c3 = acc[i][jj + 3] + bias[n + 3];
            if (RELU) {
                c0 = fmaxf(c0, 0.f); c1 = fmaxf(c1, 0.f);
                c2 = fmaxf(c2, 0.f); c3 = fmaxf(c3, 0.f);
            }
            c4.x = c0; c4.y = c1; c4.z = c2; c4.w = c3;
            *reinterpret_cast<float4*>(C + m * N + n) = c4;
        }
    }
}

// ---------------------------------------------------------------------------
// Round-6 fused GEMM+LIF (mid-tier only): in-kernel fp32->f16 2-term A split,
// UNSWIZZLED weights/LDS, 1-barrier double-buffered K loop.
// ---------------------------------------------------------------------------
template<bool SPLITX, bool PERM, bool RELU, bool WRITE_LAST, bool F16OUT>
__global__ __launch_bounds__(256, 2)
void gemm_lif(const float* __restrict__ A,
              const f16* __restrict__ Bhi, const f16* __restrict__ Blo,
              const float* __restrict__ bias,
              float* __restrict__ S, float* __restrict__ last_out,
              f16* __restrict__ Sf,
              int N, int K) {
    constexpr int BK = 32;
    constexpr int NBUF = SPLITX ? 4 : 3;
    constexpr int BUFSTR = NBUF * 4096;
    constexpr size_t SMEM = (2 * BUFSTR * 2 > 64 * 132 * 4)
                                ? (size_t)(2 * BUFSTR * 2)
                                : (size_t)(64 * 132 * 4);
    __shared__ __align__(16) char smem[SMEM];
    f16* sm = (f16*)smem;
    float (*Cs)[132] = (float (*)[132])smem;

    const int tid  = threadIdx.x;
    const int lane = tid & 63;
    const int w    = tid >> 6;
    const int wr   = w >> 1, wc = w & 1;
    const int ntile = N >> 7;
    const int bx = blockIdx.x % ntile;
    const int b  = blockIdx.x / ntile;
    const int col0 = bx << 7;

    f32x4 acc0[4][4], acc1[4][4];
#pragma unroll
    for (int mi = 0; mi < 4; ++mi)
#pragma unroll
        for (int ni = 0; ni < 4; ++ni) {
            acc0[mi][ni] = {0.f, 0.f, 0.f, 0.f};
            acc1[mi][ni] = {0.f, 0.f, 0.f, 0.f};
        }

    {
        f16* Ah0 = sm;
        f16* Bh0 = sm + 4096;
        f16* Bl0 = sm + 8192;
        f16* Al0 = sm + 12288;
#pragma unroll
        for (int p = 0; p < 2; ++p) {
            int chunk = w * 2 + p;
            int r  = chunk * 16 + (lane >> 2);
            int kq = lane & 3;
            size_t off = (size_t)(col0 + r) * K + kq * 8;
            gload_lds16(Bhi + off, Bh0 + chunk * 512);
            gload_lds16(Blo + off, Bl0 + chunk * 512);
        }
#pragma unroll
        for (int p = 0; p < 4; ++p) {
            int c = tid + p * 256;
            int r = c >> 3;
            int q = c & 7;
            const float* arow = PERM ? A + (size_t)(b * T_ + r) * K
                                     : A + (size_t)(r * B_ + b) * K;
            float4 v = *reinterpret_cast<const float4*>(arow + q * 4);
            union { f16 h[4]; uint2 u; } hi;
            hi.h[0] = (f16)v.x; hi.h[1] = (f16)v.y;
            hi.h[2] = (f16)v.z; hi.h[3] = (f16)v.w;
            *reinterpret_cast<uint2*>(&Ah0[r * BK + q * 4]) = hi.u;
            if (SPLITX) {
                union { f16 h[4]; uint2 u; } lo;
                lo.h[0] = (f16)((v.x - (float)hi.h[0]) * 4096.0f);
                lo.h[1] = (f16)((v.y - (float)hi.h[1]) * 4096.0f);
                lo.h[2] = (f16)((v.z - (float)hi.h[2]) * 4096.0f);
                lo.h[3] = (f16)((v.w - (float)hi.h[3]) * 4096.0f);
                *reinterpret_cast<uint2*>(&Al0[r * BK + q * 4]) = lo.u;
            }
        }
    }
    __syncthreads();

    const int NIT = K / BK;
    for (int it = 0; it < NIT; ++it) {
        const int cur = it & 1, nxt = cur ^ 1;
        const bool more = (it + 1 < NIT);
        const int k0n = (it + 1) * BK;

        f16* Ah_c = sm + cur * BUFSTR;
        f16* Bh_c = Ah_c + 4096;
        f16* Bl_c = Ah_c + 8192;
        f16* Al_c = Ah_c + 12288;
        f16* Ah_n = sm + nxt * BUFSTR;
        f16* Bh_n = Ah_n + 4096;
        f16* Bl_n = Ah_n + 8192;
        f16* Al_n = Ah_n + 12288;

        float4 a4[4];
        if (more) {
#pragma unroll
            for (int p = 0; p < 2; ++p) {
                int chunk = w * 2 + p;
                int r  = chunk * 16 + (lane >> 2);
                int kq = lane & 3;
                size_t off = (size_t)(col0 + r) * K + k0n + kq * 8;
                gload_lds16(Bhi + off, Bh_n + chunk * 512);
                gload_lds16(Blo + off, Bl_n + chunk * 512);
            }
#pragma unroll
            for (int p = 0; p < 4; ++p) {
                int c = tid + p * 256;
                int r = c >> 3;
                int q = c & 7;
                const float* arow = PERM ? A + (size_t)(b * T_ + r) * K
                                         : A + (size_t)(r * B_ + b) * K;
                a4[p] = *reinterpret_cast<const float4*>(arow + k0n + q * 4);
            }
        }

        {
            f16x8 ahi[4], alo[4];
#pragma unroll
            for (int mi = 0; mi < 4; ++mi) {
                int ar = (wr * 64 + mi * 16 + (lane & 15)) * BK + (lane >> 4) * 8;
                ahi[mi] = *reinterpret_cast<const f16x8*>(&Ah_c[ar]);
                if (SPLITX) alo[mi] = *reinterpret_cast<const f16x8*>(&Al_c[ar]);
            }
#pragma unroll
            for (int ni = 0; ni < 4; ++ni) {
                int br = (wc * 64 + ni * 16 + (lane & 15)) * BK + (lane >> 4) * 8;
                f16x8 bh = *reinterpret_cast<const f16x8*>(&Bh_c[br]);
                f16x8 bl = *reinterpret_cast<const f16x8*>(&Bl_c[br]);
#pragma unroll
                for (int mi = 0; mi < 4; ++mi) {
                    acc0[mi][ni] = __builtin_amdgcn_mfma_f32_16x16x32_f16(
                        ahi[mi], bh, acc0[mi][ni], 0, 0, 0);
                    acc1[mi][ni] = __builtin_amdgcn_mfma_f32_16x16x32_f16(
                        ahi[mi], bl, acc1[mi][ni], 0, 0, 0);
                    if (SPLITX)
                        acc1[mi][ni] = __builtin_amdgcn_mfma_f32_16x16x32_f16(
                            alo[mi], bh, acc1[mi][ni], 0, 0, 0);
                }
            }
        }

        if (more) {
#pragma unroll
            for (int p = 0; p < 4; ++p) {
                int c = tid + p * 256;
                int r = c >> 3;
                int q = c & 7;
                float4 v = a4[p];
                union { f16 h[4]; uint2 u; } hi;
                hi.h[0] = (f16)v.x; hi.h[1] = (f16)v.y;
                hi.h[2] = (f16)v.z; hi.h[3] = (f16)v.w;
                *reinterpret_cast<uint2*>(&Ah_n[r * BK + q * 4]) = hi.u;
                if (SPLITX) {
                    union { f16 h[4]; uint2 u; } lo;
                    lo.h[0] = (f16)((v.x - (float)hi.h[0]) * 4096.0f);
                    lo.h[1] = (f16)((v.y - (float)hi.h[1]) * 4096.0f);
                    lo.h[2] = (f16)((v.z - (float)hi.h[2]) * 4096.0f);
                    lo.h[3] = (f16)((v.w - (float)hi.h[3]) * 4096.0f);
                    *reinterpret_cast<uint2*>(&Al_n[r * BK + q * 4]) = lo.u;
                }
            }
        }
        __syncthreads();
    }

    float v = 0.f, s = 0.f;
    float* Sp = S + (size_t)b * N + col0 + (tid & 127);
    const size_t tstride = (size_t)B_ * N;

    if (wr == 0) {
#pragma unroll
        for (int ni = 0; ni < 4; ++ni) {
            int col = wc * 64 + ni * 16 + (lane & 15);
            float bv = bias[col0 + col];
#pragma unroll
            for (int mi = 0; mi < 4; ++mi) {
                int rowb = mi * 16 + ((lane >> 4) << 2);
#pragma unroll
                for (int r = 0; r < 4; ++r) {
                    float cv = acc0[mi][ni][r] + S12 * acc1[mi][ni][r] + bv;
                    if (RELU) cv = fmaxf(cv, 0.f);
                    Cs[rowb + r][col] = cv;
                }
            }
        }
    }
    __syncthreads();
    if (tid < 128) {
#pragma unroll 4
        for (int t = 0; t < 64; ++t) {
            float in = Cs[t][tid];
            v = v + (in - v) * ALPHA;
            bool sp = (v >= THR);
            s = sp ? 1.0f : 0.0f;
            Sp[(size_t)t * tstride] = s;
            if (F16OUT) Sf[((size_t)b * T_ + t) * N + col0 + tid] = (f16)s;
            v = sp ? 0.0f : v;
        }
    }
    __syncthreads();
    if (wr == 1) {
#pragma unroll
        for (int ni = 0; ni < 4; ++ni) {
            int col = wc * 64 + ni * 16 + (lane & 15);
            float bv = bias[col0 + col];
#pragma unroll
            for (int mi = 0; mi < 4; ++mi) {
                int rowb = mi * 16 + ((lane >> 4) << 2);
#pragma unroll
                for (int r = 0; r < 4; ++r) {
                    float cv = acc0[mi][ni][r] + S12 * acc1[mi][ni][r] + bv;
                    if (RELU) cv = fmaxf(cv, 0.f);
                    Cs[rowb + r][col] = cv;
                }
            }
        }
    }
    __syncthreads();
    if (tid < 128) {
#pragma unroll 4
        for (int t = 64; t < 128; ++t) {
            float in = Cs[t - 64][tid];
            v = v + (in - v) * ALPHA;
            bool sp = (v >= THR);
            s = sp ? 1.0f : 0.0f;
            Sp[(size_t)t * tstride] = s;
            if (F16OUT) Sf[((size_t)b * T_ + t) * N + col0 + tid] = (f16)s;
            v = sp ? 0.0f : v;
        }
        if (WRITE_LAST) last_out[(size_t)b * N + col0 + tid] = s;
    }
}

// ---------------------------------------------------------------------------
// Layer-0 kernel (round-10 proven structure): in-kernel x split, double-
// buffered A+B, swizzled LDS. ONLY change vs round 10: b-inner grid order
// (b = blockIdx & 255) so consecutive blocks read DISJOINT x regions —
// x is fetched once device-wide instead of once per XCD (8x).
// ---------------------------------------------------------------------------
__global__ __launch_bounds__(256, 2)
void gemm_lif_x2(const float* __restrict__ A,          // x [B][T][K]
                 const f16* __restrict__ Bhi,          // [N][K] pre-swizzled
                 const f16* __restrict__ Blo,          // [N][K] pre-swizzled
                 const float* __restrict__ bias,
                 float* __restrict__ S,                // [T][B][N] fp32 spikes
                 f16* __restrict__ Sf,                 // [B][T][N] f16 spikes
                 int N, int K) {
    constexpr int BK = 32;
    constexpr int BUFSTR = 4 * 4096;                   // Ah,Bh,Bl,Al
    __shared__ __align__(16) char smem[2 * BUFSTR * 2];   // 64 KB >= Cs 33792
    f16* sm = (f16*)smem;
    float (*Cs)[132] = (float (*)[132])smem;

    const int tid  = threadIdx.x;
    const int lane = tid & 63;
    const int w    = tid >> 6;
    const int wr   = w >> 1, wc = w & 1;
    const int b  = blockIdx.x & 255;       // batch element (inner)
    const int bx = blockIdx.x >> 8;        // feature tile (outer)
    const int col0 = bx << 7;
    const int sw = (((lane >> 4) ^ ((lane >> 1) & 3)) << 3);

    f32x4 acc0[4][4], acc1[4][4];
#pragma unroll
    for (int mi = 0; mi < 4; ++mi)
#pragma unroll
        for (int ni = 0; ni < 4; ++ni) {
            acc0[mi][ni] = {0.f, 0.f, 0.f, 0.f};
            acc1[mi][ni] = {0.f, 0.f, 0.f, 0.f};
        }

    // prologue: stage tile 0 into buffer 0
    {
        f16* Ah0 = sm;
        f16* Bh0 = sm + 4096;
        f16* Bl0 = sm + 8192;
        f16* Al0 = sm + 12288;
#pragma unroll
        for (int p = 0; p < 2; ++p) {
            int chunk = w * 2 + p;
            int r  = chunk * 16 + (lane >> 2);
            int kq = lane & 3;
            size_t off = (size_t)(col0 + r) * K + kq * 8;
            gload_lds16(Bhi + off, Bh0 + chunk * 512);
            gload_lds16(Blo + off, Bl0 + chunk * 512);
        }
#pragma unroll
        for (int p = 0; p < 4; ++p) {
            int c = tid + p * 256;
            int r = c >> 3;
            int q = c & 7;
            const float* arow = A + (size_t)(b * T_ + r) * K;
            float4 v = *reinterpret_cast<const float4*>(arow + q * 4);
            int aoff = r * 32 + ((((q >> 1) ^ ((r >> 1) & 3))) << 3) + ((q & 1) << 2);
            union { f16 h[4]; uint2 u; } hi;
            hi.h[0] = (f16)v.x; hi.h[1] = (f16)v.y;
            hi.h[2] = (f16)v.z; hi.h[3] = (f16)v.w;
            *reinterpret_cast<uint2*>(&Ah0[aoff]) = hi.u;
            union { f16 h[4]; uint2 u; } lo;
            lo.h[0] = (f16)((v.x - (float)hi.h[0]) * 4096.0f);
            lo.h[1] = (f16)((v.y - (float)hi.h[1]) * 4096.0f);
            lo.h[2] = (f16)((v.z - (float)hi.h[2]) * 4096.0f);
            lo.h[3] = (f16)((v.w - (float)hi.h[3]) * 4096.0f);
            *reinterpret_cast<uint2*>(&Al0[aoff]) = lo.u;
        }
    }
    __syncthreads();

    const int NIT = K / BK;
    for (int it = 0; it < NIT; ++it) {
        const int cur = it & 1, nxt = cur ^ 1;
        const bool more = (it + 1 < NIT);
        const int k0n = (it + 1) * BK;

        f16* Ah_c = sm + cur * BUFSTR;
        f16* Bh_c = Ah_c + 4096;
        f16* Bl_c = Ah_c + 8192;
        f16* Al_c = Ah_c + 12288;
        f16* Ah_n = sm + nxt * BUFSTR;
        f16* Bh_n = Ah_n + 4096;
        f16* Bl_n = Ah_n + 8192;
        f16* Al_n = Ah_n + 12288;

        // issue next tile's loads (B direct-to-LDS, A into registers)
        float4 a4[4];
        if (more) {
#pragma unroll
            for (int p = 0; p < 2; ++p) {
                int chunk = w * 2 + p;
                int r  = chunk * 16 + (lane >> 2);
                int kq = lane & 3;
                size_t off = (size_t)(col0 + r) * K + k0n + kq * 8;
                gload_lds16(Bhi + off, Bh_n + chunk * 512);
                gload_lds16(Blo + off, Bl_n + chunk * 512);
            }
#pragma unroll
            for (int p = 0; p < 4; ++p) {
                int c = tid + p * 256;
                int r = c >> 3;
                int q = c & 7;
                const float* arow = A + (size_t)(b * T_ + r) * K;
                a4[p] = *reinterpret_cast<const float4*>(arow + k0n + q * 4);
            }
        }

        // compute on current buffer (swizzled frag reads)
        {
            f16x8 ahi[4], alo[4];
#pragma unroll
            for (int mi = 0; mi < 4; ++mi) {
                int ar = (wr * 64 + mi * 16 + (lane & 15)) * BK + sw;
                ahi[mi] = *reinterpret_cast<const f16x8*>(&Ah_c[ar]);
                alo[mi] = *reinterpret_cast<const f16x8*>(&Al_c[ar]);
            }
#pragma unroll
            for (int ni = 0; ni < 4; ++ni) {
                int br = (wc * 64 + ni * 16 + (lane & 15)) * BK + sw;
                f16x8 bh = *reinterpret_cast<const f16x8*>(&Bh_c[br]);
                f16x8 bl = *reinterpret_cast<const f16x8*>(&Bl_c[br]);
#pragma unroll
                for (int mi = 0; mi < 4; ++mi) {
                    acc0[mi][ni] = __builtin_amdgcn_mfma_f32_16x16x32_f16(
                        ahi[mi], bh, acc0[mi][ni], 0, 0, 0);
                    acc1[mi][ni] = __builtin_amdgcn_mfma_f32_16x16x32_f16(
                        ahi[mi], bl, acc1[mi][ni], 0, 0, 0);
                    acc1[mi][ni] = __builtin_amdgcn_mfma_f32_16x16x32_f16(
                        alo[mi], bh, acc1[mi][ni], 0, 0, 0);
                }
            }
        }

        // late write: convert prefetched A regs into next buffer (swizzled)
        if (more) {
#pragma unroll
            for (int p = 0; p < 4; ++p) {
                int c = tid + p * 256;
                int r = c >> 3;
                int q = c & 7;
                float4 v = a4[p];
                int aoff = r * 32 + ((((q >> 1) ^ ((r >> 1) & 3))) << 3) + ((q & 1) << 2);
                union { f16 h[4]; uint2 u; } hi;
                hi.h[0] = (f16)v.x; hi.h[1] = (f16)v.y;
                hi.h[2] = (f16)v.z; hi.h[3] = (f16)v.w;
                *reinterpret_cast<uint2*>(&Ah_n[aoff]) = hi.u;
                union { f16 h[4]; uint2 u; } lo;
                lo.h[0] = (f16)((v.x - (float)hi.h[0]) * 4096.0f);
                lo.h[1] = (f16)((v.y - (float)hi.h[1]) * 4096.0f);
                lo.h[2] = (f16)((v.z - (float)hi.h[2]) * 4096.0f);
                lo.h[3] = (f16)((v.w - (float)hi.h[3]) * 4096.0f);
                *reinterpret_cast<uint2*>(&Al_n[aoff]) = lo.u;
            }
        }
        __syncthreads();
    }

    // two-phase epilogue: RELU + LIF + fp32 spikes + f16 mirror
    float v = 0.f;
    float* Sp = S + (size_t)b * N + col0 + (tid & 127);
    const size_t tstride = (size_t)B_ * N;

    if (wr == 0) {
#pragma unroll
        for (int ni = 0; ni < 4; ++ni) {
            int col = wc * 64 + ni * 16 + (lane & 15);
            float bv = bias[col0 + col];
#pragma unroll
            for (int mi = 0; mi < 4; ++mi) {
                int rowb = mi * 16 + ((lane >> 4) << 2);
#pragma unroll
                for (int r = 0; r < 4; ++r) {
                    float cv = fmaxf(acc0[mi][ni][r] + S12 * acc1[mi][ni][r] + bv, 0.f);
                    Cs[rowb + r][col] = cv;
                }
            }
        }
    }
    __syncthreads();
    if (tid < 128) {
#pragma unroll 4
        for (int t = 0; t < 64; ++t) {
            float in = Cs[t][tid];
            v = v + (in - v) * ALPHA;
            bool sp = (v >= THR);
            float s = sp ? 1.0f : 0.0f;
            Sp[(size_t)t * tstride] = s;
            Sf[((size_t)b * T_ + t) * N + col0 + tid] = (f16)s;
            v = sp ? 0.0f : v;
        }
    }
    __syncthreads();
    if (wr == 1) {
#pragma unroll
        for (int ni = 0; ni < 4; ++ni) {
            int col = wc * 64 + ni * 16 + (lane & 15);
            float bv = bias[col0 + col];
#pragma unroll
            for (int mi = 0; mi < 4; ++mi) {
                int rowb = mi * 16 + ((lane >> 4) << 2);
#pragma unroll
                for (int r = 0; r < 4; ++r) {
                    float cv = fmaxf(acc0[mi][ni][r] + S12 * acc1[mi][ni][r] + bv, 0.f);
                    Cs[rowb + r][col] = cv;
                }
            }
        }
    }
    __syncthreads();
    if (tid < 128) {
#pragma unroll 4
        for (int t = 64; t < 128; ++t) {
            float in = Cs[t - 64][tid];
            v = v + (in - v) * ALPHA;
            bool sp = (v >= THR);
            float s = sp ? 1.0f : 0.0f;
            Sp[(size_t)t * tstride] = s;
            Sf[((size_t)b * T_ + t) * N + col0 + tid] = (f16)s;
            v = sp ? 0.0f : v;
        }
    }
}

// ---------------------------------------------------------------------------
// f16-A consumer (L1/L2): round-8 proven structure; ONLY change: b-inner
// grid order (A read once device-wide; weight tile shared by 256 consecutive
// blocks, L2-resident per XCD).
// ---------------------------------------------------------------------------
template<bool WRITE_LAST, bool F16OUT>
__global__ __launch_bounds__(256, 3)
void gemm_lif_h(const f16* __restrict__ Af,     // [B][T][K] f16 spikes
                const f16* __restrict__ Bhi,    // [N][K] pre-swizzled
                const f16* __restrict__ Blo,    // [N][K] pre-swizzled (x 2^12)
                const float* __restrict__ bias,
                float* __restrict__ S,          // [T][B][N] fp32 spikes
                float* __restrict__ last_out,   // [B][N] (WRITE_LAST)
                f16* __restrict__ Sf,           // [B][T][N] f16 spikes (F16OUT)
                int N, int K) {
    constexpr int BK = 32;
    constexpr int BUFF = 3 * 4096;              // f16 elems: Ah, Bh, Bl
    __shared__ __align__(16) char smem[2 * BUFF * 2];   // 48 KB >= Cs 33792
    f16* sm = (f16*)smem;
    float (*Cs)[132] = (float (*)[132])smem;

    const int tid  = threadIdx.x;
    const int lane = tid & 63;
    const int w    = tid >> 6;
    const int wr   = w >> 1, wc = w & 1;
    const int b  = blockIdx.x & 255;       // batch element (inner)
    const int bx = blockIdx.x >> 8;        // feature tile (outer)
    const int col0 = bx << 7;
    const int sw = (((lane >> 4) ^ ((lane >> 1) & 3)) << 3);

    f32x4 acc0[4][4], acc1[4][4];
#pragma unroll
    for (int mi = 0; mi < 4; ++mi)
#pragma unroll
        for (int ni = 0; ni < 4; ++ni) {
            acc0[mi][ni] = {0.f, 0.f, 0.f, 0.f};
            acc1[mi][ni] = {0.f, 0.f, 0.f, 0.f};
        }

    // staging addresses (per lane)
    const int r0   = (w * 2 + 0) * 16 + (lane >> 2);
    const int r1   = (w * 2 + 1) * 16 + (lane >> 2);
    const int kqs  = lane & 3;
    const int kqa0 = kqs ^ ((r0 >> 1) & 3);
    const int kqa1 = kqs ^ ((r1 >> 1) & 3);

    // prologue: stage tile 0 into buffer 0
    {
        size_t b0 = (size_t)(col0 + r0) * K + kqs * 8;
        size_t b1 = (size_t)(col0 + r1) * K + kqs * 8;
        size_t a0 = ((size_t)b * T_ + r0) * K + kqa0 * 8;
        size_t a1 = ((size_t)b * T_ + r1) * K + kqa1 * 8;
        gload_lds16(Af + a0,  sm + (w * 2 + 0) * 512);
        gload_lds16(Af + a1,  sm + (w * 2 + 1) * 512);
        gload_lds16(Bhi + b0, sm + 4096 + (w * 2 + 0) * 512);
        gload_lds16(Bhi + b1, sm + 4096 + (w * 2 + 1) * 512);
        gload_lds16(Blo + b0, sm + 8192 + (w * 2 + 0) * 512);
        gload_lds16(Blo + b1, sm + 8192 + (w * 2 + 1) * 512);
    }
    __syncthreads();

    const int NIT = K / BK;
    for (int it = 0; it < NIT; ++it) {
        f16* cur = sm + (it & 1) * BUFF;
        if (it + 1 < NIT) {
            f16* nb = sm + ((it + 1) & 1) * BUFF;
            int k0n = (it + 1) * BK;
            size_t b0 = (size_t)(col0 + r0) * K + k0n + kqs * 8;
            size_t b1 = (size_t)(col0 + r1) * K + k0n + kqs * 8;
            size_t a0 = ((size_t)b * T_ + r0) * K + k0n + kqa0 * 8;
            size_t a1 = ((size_t)b * T_ + r1) * K + k0n + kqa1 * 8;
            gload_lds16(Af + a0,  nb + (w * 2 + 0) * 512);
            gload_lds16(Af + a1,  nb + (w * 2 + 1) * 512);
            gload_lds16(Bhi + b0, nb + 4096 + (w * 2 + 0) * 512);
            gload_lds16(Bhi + b1, nb + 4096 + (w * 2 + 1) * 512);
            gload_lds16(Blo + b0, nb + 8192 + (w * 2 + 0) * 512);
            gload_lds16(Blo + b1, nb + 8192 + (w * 2 + 1) * 512);
        }

        f16x8 af[4];
#pragma unroll
        for (int mi = 0; mi < 4; ++mi)
            af[mi] = *reinterpret_cast<const f16x8*>(
                &cur[(wr * 64 + mi * 16 + (lane & 15)) * BK + sw]);
#pragma unroll
        for (int ni = 0; ni < 4; ++ni) {
            int br = (wc * 64 + ni * 16 + (lane & 15)) * BK + sw;
            f16x8 bh = *reinterpret_cast<const f16x8*>(&cur[4096 + br]);
            f16x8 bl = *reinterpret_cast<const f16x8*>(&cur[8192 + br]);
#pragma unroll
            for (int mi = 0; mi < 4; ++mi) {
                acc0[mi][ni] = __builtin_amdgcn_mfma_f32_16x16x32_f16(
                    af[mi], bh, acc0[mi][ni], 0, 0, 0);
                acc1[mi][ni] = __builtin_amdgcn_mfma_f32_16x16x32_f16(
                    af[mi], bl, acc1[mi][ni], 0, 0, 0);
            }
        }
        __syncthreads();
    }

    // two-phase epilogue: transpose halves through Cs + LIF scan
    float v = 0.f, s = 0.f;
    float* Sp = S + (size_t)b * N + col0 + (tid & 127);
    const size_t tstride = (size_t)B_ * N;

    if (wr == 0) {
#pragma unroll
        for (int ni = 0; ni < 4; ++ni) {
            int col = wc * 64 + ni * 16 + (lane & 15);
            float bv = bias[col0 + col];
#pragma unroll
            for (int mi = 0; mi < 4; ++mi) {
                int rowb = mi * 16 + ((lane >> 4) << 2);
#pragma unroll
                for (int r = 0; r < 4; ++r)
                    Cs[rowb + r][col] = acc0[mi][ni][r] + S12 * acc1[mi][ni][r] + bv;
            }
        }
    }
    __syncthreads();
    if (tid < 128) {
#pragma unroll 4
        for (int t = 0; t < 64; ++t) {
            float in = Cs[t][tid];
            v = v + (in - v) * ALPHA;
            bool sp = (v >= THR);
            s = sp ? 1.0f : 0.0f;
            Sp[(size_t)t * tstride] = s;
            if (F16OUT) Sf[((size_t)b * T_ + t) * N + col0 + tid] = (f16)s;
            v = sp ? 0.0f : v;
        }
    }
    __syncthreads();
    if (wr == 1) {
#pragma unroll
        for (int ni = 0; ni < 4; ++ni) {
            int col = wc * 64 + ni * 16 + (lane & 15);
            float bv = bias[col0 + col];
#pragma unroll
            for (int mi = 0; mi < 4; ++mi) {
                int rowb = mi * 16 + ((lane >> 4) << 2);
#pragma unroll
                for (int r = 0; r < 4; ++r)
                    Cs[rowb + r][col] = acc0[mi][ni][r] + S12 * acc1[mi][ni][r] + bv;
            }
        }
    }
    __syncthreads();
    if (tid < 128) {
#pragma unroll 4
        for (int t = 64; t < 128; ++t) {
            float in = Cs[t - 64][tid];
            v = v + (in - v) * ALPHA;
            bool sp = (v >= THR);
            s = sp ? 1.0f : 0.0f;
            Sp[(size_t)t * tstride] = s;
            if (F16OUT) Sf[((size_t)b * T_ + t) * N + col0 + tid] = (f16)s;
            v = sp ? 0.0f : v;
        }
        if (WRITE_LAST) last_out[(size_t)b * N + col0 + tid] = s;
    }
}

// ---------------------------------------------------------------------------
// LIF time-scan (fp32 fallback path)
// ---------------------------------------------------------------------------
__global__ __launch_bounds__(256)
void lif_scan(float* __restrict__ buf, int BH, float* __restrict__ last_out) {
    int j = blockIdx.x * 256 + threadIdx.x;
    if (j >= BH) return;
    float v = 0.f;
    float last = 0.f;
    for (int t = 0; t < T_; ++t) {
        size_t idx = (size_t)t * BH + j;
        float in = buf[idx];
        v = v + (in - v) * ALPHA;
        bool sp = (v >= THR);
        last = sp ? 1.0f : 0.0f;
        buf[idx] = last;
        v = sp ? 0.0f : v;
    }
    if (last_out) last_out[j] = last;
}

// ---------------------------------------------------------------------------
// Tiled f64-accumulation fold: Wf[h][o] = sum_k W2[h][k]*Wo[k][o]  (fp32 out)
// ---------------------------------------------------------------------------
__global__ __launch_bounds__(256)
void make_wf2(const float* __restrict__ W2, const float* __restrict__ Wo,
              float* __restrict__ Wf) {
    __shared__ float w2s[64][33];
    __shared__ float wos[64][68];
    const int tid = threadIdx.x;
    const int ht = blockIdx.x >> 3, ot = blockIdx.x & 7;
    const int h0 = ht * 32, o0 = ot * 64;
    const int th = tid >> 3;
    const int to = tid & 7;

    double acc[8] = {0, 0, 0, 0, 0, 0, 0, 0};

    for (int k0 = 0; k0 < H_; k0 += 64) {
#pragma unroll
        for (int p = 0; p < 2; ++p) {
            int f = tid + p * 256;
            int i = f >> 4;
            int j4 = (f & 15) << 2;
            float4 v = *reinterpret_cast<const float4*>(
                W2 + (size_t)(h0 + i) * H_ + k0 + j4);
            w2s[j4 + 0][i] = v.x; w2s[j4 + 1][i] = v.y;
            w2s[j4 + 2][i] = v.z; w2s[j4 + 3][i] = v.w;
        }
#pragma unroll
        for (int p = 0; p < 4; ++p) {
            int f = tid + p * 256;
            int r = f >> 4;
            int c4 = (f & 15) << 2;
            float4 v = *reinterpret_cast<const float4*>(
                Wo + (size_t)(k0 + r) * O_ + o0 + c4);
            wos[r][c4 + 0] = v.x; wos[r][c4 + 1] = v.y;
            wos[r][c4 + 2] = v.z; wos[r][c4 + 3] = v.w;
        }
        __syncthreads();

#pragma unroll 8
        for (int k = 0; k < 64; ++k) {
            double a = (double)w2s[k][th];
#pragma unroll
            for (int j = 0; j < 8; ++j)
                acc[j] += a * (double)wos[k][to * 8 + j];
        }
        __syncthreads();
    }
#pragma unroll
    for (int j = 0; j < 8; ++j)
        Wf[(size_t)(h0 + th) * O_ + o0 + to * 8 + j] = (float)acc[j];
}

// bf[o] = bo[o] + sum_h b2[h]*Wo[h][o]  (f64 accum, serial; mid/fallback)
__global__ __launch_bounds__(256)
void make_bf(const float* __restrict__ Wo, const float* __restrict__ b2,
             const float* __restrict__ bo, float* __restrict__ bf) {
    int o = blockIdx.x * 256 + threadIdx.x;
    if (o >= O_) return;
    double acc = (double)bo[o];
    for (int h = 0; h < H_; ++h)
        acc += (double)b2[h] * (double)Wo[(size_t)h * O_ + o];
    bf[o] = (float)acc;
}

// Parallel make_bf (hi-tier): coalesced Wo reads, f64 tree reduce.
__global__ __launch_bounds__(256)
void make_bf2(const float* __restrict__ Wo, const float* __restrict__ b2,
              const float* __restrict__ bo, float* __restrict__ bf) {
    __shared__ double red[4][64];
    const int tid  = threadIdx.x;
    const int ol   = tid & 63;
    const int part = tid >> 6;                  // 0..3
    const int o    = blockIdx.x * 64 + ol;      // grid = O_/64 = 8
    double acc = 0.0;
    for (int h = part; h < H_; h += 4)
        acc += (double)b2[h] * (double)Wo[(size_t)h * O_ + o];
    red[part][ol] = acc;
    __syncthreads();
    if (part == 0) {
        double s = red[0][ol] + red[1][ol] + red[2][ol] + red[3][ol];
        bf[o] = (float)((double)bo[o] + s);
    }
}

// 2-term scaled fp16 split of W [K][N], TRANSPOSED [N][K] (mid-tier version).
template<bool SWZ>
__global__ __launch_bounds__(256)
void split_w16(const float* __restrict__ W, f16* __restrict__ hi,
               f16* __restrict__ lo, int K, int N) {
    int idx = blockIdx.x * 256 + threadIdx.x;     // idx = n*K + k_stored
    if (idx >= K * N) return;
    int n = idx / K;
    int ks = idx - n * K;
    int k = SWZ ? ((ks & ~31) | ((((ks >> 3) & 3) ^ ((n >> 1) & 3)) << 3) | (ks & 7))
                : ks;
    float wv = W[(size_t)k * N + n];
    f16 h0 = (f16)wv;
    float r = (wv - (float)h0) * 4096.0f;
    f16 h1 = (f16)r;
    hi[idx] = h0; lo[idx] = h1;
}

// Coalesced transpose-split (hi-tier): 64x64 f32 tile through LDS.
template<bool SWZ>
__global__ __launch_bounds__(256)
void split_w16t(const float* __restrict__ W, f16* __restrict__ hi,
                f16* __restrict__ lo, int K, int N) {
    __shared__ float tile[64][65];
    const int tid = threadIdx.x;
    const int ntile = N >> 6;
    const int kt = blockIdx.x / ntile;
    const int nt = blockIdx.x % ntile;
    const int k0 = kt << 6, n0 = nt << 6;

#pragma unroll
    for (int p = 0; p < 4; ++p) {
        int lin = p * 256 + tid;
        int r = lin >> 4;
        int c = (lin & 15) << 2;
        float4 v = *reinterpret_cast<const float4*>(
            W + (size_t)(k0 + r) * N + n0 + c);
        tile[r][c + 0] = v.x; tile[r][c + 1] = v.y;
        tile[r][c + 2] = v.z; tile[r][c + 3] = v.w;
    }
    __syncthreads();

    const int nl = tid >> 2;
    const int q  = tid & 3;
    const int n  = n0 + nl;
#pragma unroll
    for (int half = 0; half < 2; ++half) {
        union { f16 h[8]; uint4 u4; } Hh, Hl;
#pragma unroll
        for (int j = 0; j < 8; ++j) {
            int ksl = q * 16 + half * 8 + j;
            int kl  = SWZ ? ((ksl & ~31) |
                             ((((ksl >> 3) & 3) ^ ((n >> 1) & 3)) << 3) |
                             (ksl & 7))
                          : ksl;
            float wv = tile[kl][nl];
            f16 h0 = (f16)wv;
            float rr = (wv - (float)h0) * 4096.0f;
            Hh.h[j] = h0; Hl.h[j] = (f16)rr;
        }
        size_t off = (size_t)n * K + k0 + q * 16 + half * 8;
        *reinterpret_cast<uint4*>(hi + off) = Hh.u4;
        *reinterpret_cast<uint4*>(lo + off) = Hl.u4;
    }
}

// ---------------------------------------------------------------------------
extern "C" void kernel_launch(void* const* d_in, const int* in_sizes, int n_in,
                              void* d_out, int out_size, void* d_ws, size_t ws_size,
                              hipStream_t stream) {
    const float* x  = (const float*)d_in[0];
    const float* We = (const float*)d_in[1];
    const float* be = (const float*)d_in[2];
    const float* W1 = (const float*)d_in[3];
    const float* b1 = (const float*)d_in[4];
    const float* W2 = (const float*)d_in[5];
    const float* b2 = (const float*)d_in[6];
    const float* Wo = (const float*)d_in[7];
    const float* bo = (const float*)d_in[8];

    float* out = (float*)d_out;
    float* so_last = out;                              // [B, O]
    float* S1 = out + (size_t)B_ * O_;                 // [T, B, H]
    float* S2 = S1 + (size_t)T_ * B_ * H_;             // [T, B, H]
    float* SO = S2 + (size_t)T_ * B_ * H_;             // [T, B, O]

    const int TB = T_ * B_;
    dim3 blk(256);

    const size_t MB = 1024 * 1024;
    const size_t sz_s1f = (size_t)T_ * B_ * H_ * 2;    // 64 MiB

    // ---- hi-tier layout (~144.7 MiB) ----
    const size_t b_weh = 0;                  // 1 MB (swizzled)
    const size_t b_wel = 1 * MB;
    const size_t b_w1h = 2 * MB;             // 2 MB swizzled
    const size_t b_w1l = 4 * MB;
    const size_t b_wfh = 6 * MB;             // 1 MB swizzled
    const size_t b_wfl = 7 * MB;
    const size_t b_bf  = 8 * MB;
    const size_t b_wf  = 8 * MB + 4096;
    const size_t b_s1f = 10 * MB + 4096;
    const size_t b_s2f = b_s1f + sz_s1f;
    const size_t need_hi = b_s2f + sz_s1f;

    // ---- mid-tier (round-6) layout (~10.1 MiB) ----
    const size_t m_weh = 0;
    const size_t m_wel = m_weh + (size_t)I_ * H_ * 2;
    const size_t m_w1h = m_wel + (size_t)I_ * H_ * 2;
    const size_t m_w1l = m_w1h + (size_t)H_ * H_ * 2;
    const size_t m_wf  = m_w1l + (size_t)H_ * H_ * 2;
    const size_t m_bf  = m_wf + (size_t)H_ * O_ * 4;
    const size_t m_wfh = m_bf + (size_t)O_ * 4;
    const size_t m_wfl = m_wfh + (size_t)H_ * O_ * 2;
    const size_t need_mid = m_wfl + (size_t)H_ * O_ * 2;

    if (ws_size >= need_hi) {
        char* ws = (char*)d_ws;
        f16*   weh = (f16*)(ws + b_weh);
        f16*   wel = (f16*)(ws + b_wel);
        f16*   w1h = (f16*)(ws + b_w1h);
        f16*   w1l = (f16*)(ws + b_w1l);
        f16*   wfh = (f16*)(ws + b_wfh);
        f16*   wfl = (f16*)(ws + b_wfl);
        float* bf  = (float*)(ws + b_bf);
        float* Wf  = (float*)(ws + b_wf);
        f16*   s1f = (f16*)(ws + b_s1f);
        f16*   s2f = (f16*)(ws + b_s2f);

        // ---- prep (deterministic, every call; coalesced variants) ----
        split_w16t<true><<<dim3((I_ >> 6) * (H_ >> 6)), blk, 0, stream>>>(We, weh, wel, I_, H_);
        split_w16t<true><<<dim3((H_ >> 6) * (H_ >> 6)), blk, 0, stream>>>(W1, w1h, w1l, H_, H_);
        make_wf2<<<dim3(256), blk, 0, stream>>>(W2, Wo, Wf);
        make_bf2<<<dim3(O_ / 64), blk, 0, stream>>>(Wo, b2, bo, bf);
        split_w16t<true><<<dim3((H_ >> 6) * (O_ >> 6)), blk, 0, stream>>>(Wf, wfh, wfl, H_, O_);

        // ---- Layer 0: S1 + s1f = LIF(relu(x @ We + be))  (b-inner grid) ----
        gemm_lif_x2<<<dim3(B_ * (H_ / 128)), blk, 0, stream>>>(
            x, weh, wel, be, S1, s1f, H_, I_);

        // ---- Layer 1: S2 + s2f = LIF(s1f @ W1 + b1)  (pure f16-A) ----
        gemm_lif_h<false, true><<<dim3(B_ * (H_ / 128)), blk, 0, stream>>>(
            s1f, w1h, w1l, b1, S2, nullptr, s2f, H_, H_);

        // ---- Layer 2: SO = LIF(s2f @ (W2@Wo) + bf), so_last ----
        gemm_lif_h<true, false><<<dim3(B_ * (O_ / 128)), blk, 0, stream>>>(
            s2f, wfh, wfl, bf, SO, so_last, nullptr, O_, H_);
    } else if (ws_size >= need_mid) {
        // ---- mid-tier: round-6 proven path ----
        char* ws = (char*)d_ws;
        f16*   weh = (f16*)(ws + m_weh);
        f16*   wel = (f16*)(ws + m_wel);
        f16*   w1h = (f16*)(ws + m_w1h);
        f16*   w1l = (f16*)(ws + m_w1l);
        float* Wf  = (float*)(ws + m_wf);
        float* bf  = (float*)(ws + m_bf);
        f16*   wfh = (f16*)(ws + m_wfh);
        f16*   wfl = (f16*)(ws + m_wfl);

        split_w16<false><<<dim3((I_ * H_ + 255) / 256), blk, 0, stream>>>(We, weh, wel, I_, H_);
        split_w16<false><<<dim3((H_ * H_ + 255) / 256), blk, 0, stream>>>(W1, w1h, w1l, H_, H_);
        make_wf2<<<dim3(256), blk, 0, stream>>>(W2, Wo, Wf);
        make_bf<<<dim3(2), blk, 0, stream>>>(Wo, b2, bo, bf);
        split_w16<false><<<dim3((H_ * O_ + 255) / 256), blk, 0, stream>>>(Wf, wfh, wfl, H_, O_);

        gemm_lif<true, true, true, false, false><<<dim3(B_ * (H_ / 128)), blk, 0, stream>>>(
            x, weh, wel, be, S1, nullptr, nullptr, H_, I_);
        gemm_lif<false, false, false, false, false><<<dim3(B_ * (H_ / 128)), blk, 0, stream>>>(
            S1, w1h, w1l, b1, S2, nullptr, nullptr, H_, H_);
        gemm_lif<false, false, false, true, false><<<dim3(B_ * (O_ / 128)), blk, 0, stream>>>(
            S2, wfh, wfl, bf, SO, so_last, nullptr, O_, H_);
    } else {
        // ---- deep fallback: fp32 folded path (~2.1 MB ws) ----
        float* Wf = (float*)d_ws;
        float* bf = Wf + (size_t)H_ * O_;
        gemm128<true, true><<<dim3((TB / 128) * (H_ / 128)), blk, 0, stream>>>(
            x, We, be, S1, TB, H_, I_);
        lif_scan<<<dim3((B_ * H_ + 255) / 256), blk, 0, stream>>>(S1, B_ * H_, nullptr);
        gemm128<false, false><<<dim3((TB / 128) * (H_ / 128)), blk, 0, stream>>>(
            S1, W1, b1, S2, TB, H_, H_);
        lif_scan<<<dim3((B_ * H_ + 255) / 256), blk, 0, stream>>>(S2, B_ * H_, nullptr);
        make_wf2<<<dim3(256), blk, 0, stream>>>(W2, Wo, Wf);
        make_bf<<<dim3(2), blk, 0, stream>>>(Wo, b2, bo, bf);
        gemm128<false, false><<<dim3((TB / 128) * (O_ / 128)), blk, 0, stream>>>(
            S2, Wf, bf, SO, TB, O_, H_);
        lif_scan<<<dim3((B_ * O_ + 255) / 256), blk, 0, stream>>>(SO, B_ * O_, so_last);
    }
}